// Round 6
// baseline (854.147 us; speedup 1.0000x reference)
//
#include <hip/hip_runtime.h>
#include <hip/hip_bf16.h>
#include <hip/hip_cooperative_groups.h>

namespace cg = cooperative_groups;

#define WID 32
#define KER 6
#define DEPTH 4
#define WEXT_ELEMS (33 * 2 * 64 * 8)   // steps x ntiles x lanes x 8
#define NB 256                          // cooperative grid blocks (1/CU guaranteed)
#define NT 512                          // threads per block

typedef __attribute__((ext_vector_type(8))) short bf16x8;
typedef __attribute__((ext_vector_type(4))) float f32x4;

static __device__ __forceinline__ float bf2f(unsigned short u) {
  union { unsigned int u; float f; } v; v.u = ((unsigned int)u) << 16; return v.f;
}
static __device__ __forceinline__ unsigned short f2bf(float f) {
  union { float f; unsigned int u; } v; v.f = f;
  unsigned int r = v.u + 0x7fffu + ((v.u >> 16) & 1u);
  return (unsigned short)(r >> 16);
}

// ---- shared msg inner step: 2 tiles (32 edges) per wave iteration ----
// z[e, kk=kh*32+i] = h_src[e][i]*h3[e][kh]; msg = [z ; h_src] @ [Wf ; B3]
static __device__ __forceinline__ void msg_supertile(
    const unsigned short* __restrict__ hbf, const unsigned short* __restrict__ h3s,
    const int* __restrict__ ssrc, int ecnt, unsigned short* __restrict__ msgbuf,
    const unsigned short* wlds, int st, int lane) {
  const int g = lane >> 4, eo = lane & 15;
  const int ebase = st * 32;
  int eA = min(ebase + eo, ecnt - 1);
  int eB = min(ebase + 16 + eo, ecnt - 1);
  const uint4* hA = (const uint4*)(h3s + (size_t)eA * WID);
  const uint4* hB = (const uint4*)(h3s + (size_t)eB * WID);
  uint4 qa0 = hA[0], qa1 = hA[1], qa2 = hA[2], qa3 = hA[3];
  uint4 qb0 = hB[0], qb1 = hB[1], qb2 = hB[2], qb3 = hB[3];
  unsigned int hwA[16], hwB[16];
  hwA[0]=qa0.x; hwA[1]=qa0.y; hwA[2]=qa0.z; hwA[3]=qa0.w;
  hwA[4]=qa1.x; hwA[5]=qa1.y; hwA[6]=qa1.z; hwA[7]=qa1.w;
  hwA[8]=qa2.x; hwA[9]=qa2.y; hwA[10]=qa2.z; hwA[11]=qa2.w;
  hwA[12]=qa3.x; hwA[13]=qa3.y; hwA[14]=qa3.z; hwA[15]=qa3.w;
  hwB[0]=qb0.x; hwB[1]=qb0.y; hwB[2]=qb0.z; hwB[3]=qb0.w;
  hwB[4]=qb1.x; hwB[5]=qb1.y; hwB[6]=qb1.z; hwB[7]=qb1.w;
  hwB[8]=qb2.x; hwB[9]=qb2.y; hwB[10]=qb2.z; hwB[11]=qb2.w;
  hwB[12]=qb3.x; hwB[13]=qb3.y; hwB[14]=qb3.z; hwB[15]=qb3.w;
  int srcA = ssrc[eA], srcB = ssrc[eB];
  uint4 ha4 = *(const uint4*)(hbf + (size_t)srcA * WID + g * 8);
  uint4 hb4 = *(const uint4*)(hbf + (size_t)srcB * WID + g * 8);
  bf16x8 hsvA = __builtin_bit_cast(bf16x8, ha4);
  bf16x8 hsvB = __builtin_bit_cast(bf16x8, hb4);
  float hfA[8], hfB[8];
  #pragma unroll
  for (int j = 0; j < 8; j++) { hfA[j] = bf2f((unsigned short)hsvA[j]); hfB[j] = bf2f((unsigned short)hsvB[j]); }
  f32x4 accA0 = {0.f,0.f,0.f,0.f}, accA1 = {0.f,0.f,0.f,0.f};
  f32x4 accB0 = {0.f,0.f,0.f,0.f}, accB1 = {0.f,0.f,0.f,0.f};
  #pragma unroll
  for (int s = 0; s < 32; s++) {
    unsigned int wa = hwA[s >> 1], wb = hwB[s >> 1];
    unsigned int fa = (s & 1) ? (wa & 0xffff0000u) : (wa << 16);
    unsigned int fbm = (s & 1) ? (wb & 0xffff0000u) : (wb << 16);
    float h3A = __builtin_bit_cast(float, fa);
    float h3B = __builtin_bit_cast(float, fbm);
    float a0 = h3A*hfA[0], a1 = h3A*hfA[1], a2 = h3A*hfA[2], a3 = h3A*hfA[3];
    float a4 = h3A*hfA[4], a5 = h3A*hfA[5], a6 = h3A*hfA[6], a7 = h3A*hfA[7];
    float c0 = h3B*hfB[0], c1 = h3B*hfB[1], c2 = h3B*hfB[2], c3 = h3B*hfB[3];
    float c4 = h3B*hfB[4], c5 = h3B*hfB[5], c6 = h3B*hfB[6], c7 = h3B*hfB[7];
    uint4 awA, awB;
    asm("v_cvt_pk_bf16_f32 %0, %1, %2" : "=v"(awA.x) : "v"(a0), "v"(a1));
    asm("v_cvt_pk_bf16_f32 %0, %1, %2" : "=v"(awA.y) : "v"(a2), "v"(a3));
    asm("v_cvt_pk_bf16_f32 %0, %1, %2" : "=v"(awA.z) : "v"(a4), "v"(a5));
    asm("v_cvt_pk_bf16_f32 %0, %1, %2" : "=v"(awA.w) : "v"(a6), "v"(a7));
    asm("v_cvt_pk_bf16_f32 %0, %1, %2" : "=v"(awB.x) : "v"(c0), "v"(c1));
    asm("v_cvt_pk_bf16_f32 %0, %1, %2" : "=v"(awB.y) : "v"(c2), "v"(c3));
    asm("v_cvt_pk_bf16_f32 %0, %1, %2" : "=v"(awB.z) : "v"(c4), "v"(c5));
    asm("v_cvt_pk_bf16_f32 %0, %1, %2" : "=v"(awB.w) : "v"(c6), "v"(c7));
    bf16x8 afA = __builtin_bit_cast(bf16x8, awA);
    bf16x8 afB = __builtin_bit_cast(bf16x8, awB);
    bf16x8 w0 = *(const bf16x8*)&wlds[((s * 2 + 0) * 64 + lane) * 8];
    bf16x8 w1 = *(const bf16x8*)&wlds[((s * 2 + 1) * 64 + lane) * 8];
    accA0 = __builtin_amdgcn_mfma_f32_16x16x32_bf16(afA, w0, accA0, 0, 0, 0);
    accA1 = __builtin_amdgcn_mfma_f32_16x16x32_bf16(afA, w1, accA1, 0, 0, 0);
    accB0 = __builtin_amdgcn_mfma_f32_16x16x32_bf16(afB, w0, accB0, 0, 0, 0);
    accB1 = __builtin_amdgcn_mfma_f32_16x16x32_bf16(afB, w1, accB1, 0, 0, 0);
  }
  { // bias rows
    bf16x8 w0 = *(const bf16x8*)&wlds[((32 * 2 + 0) * 64 + lane) * 8];
    bf16x8 w1 = *(const bf16x8*)&wlds[((32 * 2 + 1) * 64 + lane) * 8];
    accA0 = __builtin_amdgcn_mfma_f32_16x16x32_bf16(hsvA, w0, accA0, 0, 0, 0);
    accA1 = __builtin_amdgcn_mfma_f32_16x16x32_bf16(hsvA, w1, accA1, 0, 0, 0);
    accB0 = __builtin_amdgcn_mfma_f32_16x16x32_bf16(hsvB, w0, accB0, 0, 0, 0);
    accB1 = __builtin_amdgcn_mfma_f32_16x16x32_bf16(hsvB, w1, accB1, 0, 0, 0);
  }
  // D layout (m89): col = lane&15 (channel), row = (lane>>4)*4+r (edge slot)
  #pragma unroll
  for (int r = 0; r < 4; r++) {
    int oeA = ebase + g * 4 + r;
    int oeB = ebase + 16 + g * 4 + r;
    if (oeA < ecnt) {
      msgbuf[(size_t)oeA * WID + eo]      = f2bf(accA0[r]);
      msgbuf[(size_t)oeA * WID + 16 + eo] = f2bf(accA1[r]);
    }
    if (oeB < ecnt) {
      msgbuf[(size_t)oeB * WID + eo]      = f2bf(accB0[r]);
      msgbuf[(size_t)oeB * WID + 16 + eo] = f2bf(accB1[r]);
    }
  }
}

// ======================= cooperative mega-kernel ======================
struct MegaArgs {
  const float *x; const int *ei; const float *ea; const int *eib; const float *eab;
  const float *fc1w, *fc1b;
  const float *k1w1, *k1b1, *k1w2, *k1b2, *k1w3, *k1b3;
  const float *k2w1, *k2b1, *k2w2, *k2b2, *k2w3, *k2b3;
  const float *root1, *bias1, *root2, *bias2, *fc2w, *fc2b;
  float* out;
  unsigned short *h3s1, *h3s2, *w1b, *w2b, *hbf;
  float* h;
  unsigned short *msg1, *msg2;
  unsigned int *cnt12, *start1, *start2, *rank1, *rank2, *partials;
  int *ssrc1, *ssrc2;
  int n_nodes, E, EB, B1;
};

__launch_bounds__(NT)
__global__ void k_mega(MegaArgs a) {
  __shared__ __align__(16) unsigned short wlds[WEXT_ELEMS];  // 67584 B
  __shared__ float rs[WID * WID];
  __shared__ float bs[WID];
  __shared__ unsigned int sscan[NT];
  cg::grid_group grid = cg::this_grid();
  const int tid = threadIdx.x, bid = blockIdx.x;
  const int gtid = bid * NT + tid, gsz = NB * NT;
  const int n_nodes = a.n_nodes, E = a.E, EB = a.EB, B1 = a.B1;
  const int n2 = 2 * n_nodes;

  // ---- P0: zero counts, h0, pack Wext, stage root/bias --------------
  for (int i = gtid; i < n2; i += gsz) a.cnt12[i] = 0u;
  for (int i = gtid; i < n_nodes * WID; i += gsz) {
    int n = i >> 5, o = i & 31;
    float v = a.x[n] * a.fc1w[o] + a.fc1b[o];
    a.h[i] = v; a.hbf[i] = f2bf(v);
  }
  for (int i = gtid; i < 2 * WEXT_ELEMS; i += gsz) {
    int which = i >= WEXT_ELEMS;
    int id2 = which ? i - WEXT_ELEMS : i;
    const float* w3 = which ? a.k2w3 : a.k1w3;
    const float* b3 = which ? a.k2b3 : a.k1b3;
    unsigned short* outp = which ? a.w2b : a.w1b;
    int j = id2 & 7, l = (id2 >> 3) & 63, tt = (id2 >> 9) & 1, s = id2 >> 10;
    int p = ((l >> 4) << 3) + j;
    int o = tt * 16 + (l & 15);
    float v = (s < 32) ? w3[s * 1024 + p * 32 + o] : b3[p * 32 + o];
    outp[id2] = f2bf(v);
  }
  for (int i = tid; i < WID * WID; i += NT) rs[i] = a.root1[i] + a.root2[i];
  if (tid < WID) bs[tid] = a.bias1[tid] + a.bias2[tid];
  grid.sync();

  // ---- P1: degree histogram + rank ---------------------------------
  for (int i = gtid; i < E + EB; i += gsz) {
    if (i < E) a.rank1[i] = atomicAdd(&a.cnt12[a.ei[E + i]], 1u);
    else { int e = i - E; a.rank2[e] = atomicAdd(&a.cnt12[n_nodes + a.eib[EB + e]], 1u); }
  }
  grid.sync();

  // ---- P2: 3-phase exclusive scan of cnt1||cnt2 ---------------------
  const int nbS = (n2 + NT - 1) / NT;
  if (bid < nbS) {
    int i = bid * NT + tid;
    unsigned int v = (i < n2) ? a.cnt12[i] : 0u;
    sscan[tid] = v; __syncthreads();
    for (int d = NT / 2; d > 0; d >>= 1) { if (tid < d) sscan[tid] += sscan[tid + d]; __syncthreads(); }
    if (tid == 0) a.partials[bid] = sscan[0];
  }
  grid.sync();
  if (bid == 0) {
    unsigned int v = (tid < nbS) ? a.partials[tid] : 0u;
    sscan[tid] = v; __syncthreads();
    for (int d = 1; d < NT; d <<= 1) { unsigned int u = (tid >= d) ? sscan[tid - d] : 0u; __syncthreads(); sscan[tid] += u; __syncthreads(); }
    if (tid < nbS) a.partials[tid] = sscan[tid] - v;
  }
  grid.sync();
  if (bid < nbS) {
    int i = bid * NT + tid;
    unsigned int v = (i < n2) ? a.cnt12[i] : 0u;
    sscan[tid] = v; __syncthreads();
    for (int d = 1; d < NT; d <<= 1) { unsigned int u = (tid >= d) ? sscan[tid - d] : 0u; __syncthreads(); sscan[tid] += u; __syncthreads(); }
    unsigned int ex = sscan[tid] - v + a.partials[bid];
    if (i < n_nodes) a.start1[i] = ex;
    else if (i < n2) a.start2[i - n_nodes] = ex - (unsigned int)E;
  }
  grid.sync();

  // ---- P3: edge MLP + fused scatter (role-split) --------------------
  {
    bool role1 = bid < B1;
    const float* w1 = role1 ? a.k1w1 : a.k2w1;
    const float* b1 = role1 ? a.k1b1 : a.k2b1;
    const float* w2 = role1 ? a.k1w2 : a.k2w2;
    const float* b2 = role1 ? a.k1b2 : a.k2b2;
    float* sw = (float*)sscan;   // layout: w1@0(48) b1@64(8) w2@128(256) b2@384(32)
    if (tid < KER * 8) sw[tid] = w1[tid];
    if (tid >= 64 && tid < 72) sw[tid] = b1[tid - 64];
    if (tid >= 128 && tid < 384) sw[tid] = w2[tid - 128];
    if (tid >= 384 && tid < 416) sw[tid] = b2[tid - 384];
    __syncthreads();
    const int ecnt = role1 ? E : EB;
    const float* ea = role1 ? a.ea : a.eab;
    const int* eidx = role1 ? a.ei : a.eib;
    const unsigned int* rank = role1 ? a.rank1 : a.rank2;
    const unsigned int* start = role1 ? a.start1 : a.start2;
    unsigned short* h3s = role1 ? a.h3s1 : a.h3s2;
    int* ssrc = role1 ? a.ssrc1 : a.ssrc2;
    int blk0 = role1 ? bid : bid - B1;
    int rblocks = role1 ? B1 : NB - B1;
    for (int e = blk0 * NT + tid; e < ecnt; e += rblocks * NT) {
      float aa[KER];
      #pragma unroll
      for (int i = 0; i < KER; i++) aa[i] = ea[e * KER + i];
      float h8[8];
      #pragma unroll
      for (int o = 0; o < 8; o++) {
        float s = sw[64 + o];
        #pragma unroll
        for (int i = 0; i < KER; i++) s += aa[i] * sw[i * 8 + o];
        h8[o] = fmaxf(s, 0.f);
      }
      int d = eidx[ecnt + e];
      unsigned int p = start[d] + rank[e];
      ssrc[p] = eidx[e];
      size_t base = (size_t)p * WID;
      #pragma unroll
      for (int o = 0; o < WID; o++) {
        float s = sw[384 + o];
        #pragma unroll
        for (int i = 0; i < 8; i++) s += h8[i] * sw[128 + i * 32 + o];
        h3s[base + o] = f2bf(fmaxf(s, 0.f));
      }
    }
  }
  grid.sync();

  // ---- P4: load role Wext into LDS ONCE (persists across layers) ----
  {
    const unsigned short* wsrc = (bid < B1) ? a.w1b : a.w2b;
    const uint4* s4 = (const uint4*)wsrc;
    uint4* d4 = (uint4*)wlds;
    for (int i = tid; i < WEXT_ELEMS / 8; i += NT) d4[i] = s4[i];
  }
  __syncthreads();

  // ---- layers -------------------------------------------------------
  const int lane = tid & 63, wv = tid >> 6;
  for (int t = 0; t < DEPTH; t++) {
    {  // msg phase (role-split, 32 edges per wave iteration)
      bool role1 = bid < B1;
      const unsigned short* h3s = role1 ? a.h3s1 : a.h3s2;
      const int* ssrc = role1 ? a.ssrc1 : a.ssrc2;
      unsigned short* msgbuf = role1 ? a.msg1 : a.msg2;
      int ecnt = role1 ? E : EB;
      int blk0 = role1 ? bid : bid - B1;
      int rblocks = role1 ? B1 : NB - B1;
      int nst = (ecnt + 31) >> 5;
      int wpb = NT >> 6, nwv = rblocks * wpb;
      for (int st = blk0 * wpb + wv; st < nst; st += nwv)
        msg_supertile(a.hbf, h3s, ssrc, ecnt, msgbuf, wlds, st, lane);
    }
    grid.sync();
    {  // update phase (all blocks)
      int last = (t == DEPTH - 1);
      for (int idx = gtid; idx < n_nodes * WID; idx += gsz) {
        int n = idx >> 5, o = idx & 31;
        unsigned int b1v = a.start1[n], c1v = a.cnt12[n];
        unsigned int b2v = a.start2[n], c2v = a.cnt12[n_nodes + n];
        float s1 = 0.f, s2 = 0.f;
        for (unsigned int k = 0; k < c1v; k++) s1 += bf2f(a.msg1[(size_t)(b1v + k) * WID + o]);
        for (unsigned int k = 0; k < c2v; k++) s2 += bf2f(a.msg2[(size_t)(b2v + k) * WID + o]);
        float v = s1 / (float)(c1v ? c1v : 1u) + s2 / (float)(c2v ? c2v : 1u) + bs[o];
        const float* hrow = a.h + (size_t)n * WID;
        #pragma unroll
        for (int i = 0; i < WID; i++) v += hrow[i] * rs[i * WID + o];
        v = fmaxf(v, 0.f);
        a.h[idx] = v;                 // row read by same wave only (lockstep-safe)
        a.hbf[idx] = f2bf(v);
        if (last) {
          float pv = v * a.fc2w[o];
          #pragma unroll
          for (int m = 16; m >= 1; m >>= 1) pv += __shfl_xor(pv, m, 32);
          if (o == 0) a.out[n] = pv + a.fc2b[0];
        }
      }
    }
    if (t < DEPTH - 1) grid.sync();
  }
}

// ================== fallback multi-dispatch path (round-5) ============
__global__ void k_h0(const float* __restrict__ x, const float* __restrict__ w,
                     const float* __restrict__ b, float* __restrict__ h,
                     unsigned short* __restrict__ hbf, int n_nodes) {
  int gid = blockIdx.x * blockDim.x + threadIdx.x;
  if (gid >= n_nodes * WID) return;
  int n = gid >> 5, o = gid & 31;
  float v = x[n] * w[o] + b[o];
  h[gid] = v;
  hbf[gid] = f2bf(v);
}

__global__ void k_cnt(const int* __restrict__ ei, int E,
                      const int* __restrict__ eib, int EB,
                      unsigned int* __restrict__ cnt1, unsigned int* __restrict__ cnt2,
                      unsigned int* __restrict__ rank1, unsigned int* __restrict__ rank2) {
  int idx = blockIdx.x * blockDim.x + threadIdx.x;
  if (idx < E) {
    rank1[idx] = atomicAdd(&cnt1[ei[E + idx]], 1u);
  } else if (idx < E + EB) {
    int e = idx - E;
    rank2[e] = atomicAdd(&cnt2[eib[EB + e]], 1u);
  }
}

__global__ void k_scan1(const unsigned int* __restrict__ cnt, unsigned int* __restrict__ partials,
                        int n2) {
  __shared__ unsigned int s[256];
  int t = threadIdx.x;
  int i = blockIdx.x * 256 + t;
  unsigned int v = (i < n2) ? cnt[i] : 0u;
  s[t] = v;
  __syncthreads();
  for (int d = 128; d > 0; d >>= 1) {
    if (t < d) s[t] += s[t + d];
    __syncthreads();
  }
  if (t == 0) partials[blockIdx.x] = s[0];
}

__global__ void k_scan2(unsigned int* __restrict__ partials, int nb) {
  __shared__ unsigned int s[1024];
  int t = threadIdx.x;
  unsigned int v = (t < nb) ? partials[t] : 0u;
  s[t] = v;
  __syncthreads();
  for (int d = 1; d < 1024; d <<= 1) {
    unsigned int u = (t >= d) ? s[t - d] : 0u;
    __syncthreads();
    s[t] += u;
    __syncthreads();
  }
  if (t < nb) partials[t] = s[t] - v;
}

__global__ void k_scan3(const unsigned int* __restrict__ cnt, const unsigned int* __restrict__ partials,
                        unsigned int* __restrict__ start1, unsigned int* __restrict__ start2,
                        int n, int Etot) {
  __shared__ unsigned int s[256];
  int t = threadIdx.x;
  int i = blockIdx.x * 256 + t;
  int n2 = 2 * n;
  unsigned int v = (i < n2) ? cnt[i] : 0u;
  s[t] = v;
  __syncthreads();
  for (int d = 1; d < 256; d <<= 1) {
    unsigned int u = (t >= d) ? s[t - d] : 0u;
    __syncthreads();
    s[t] += u;
    __syncthreads();
  }
  unsigned int ex = s[t] - v + partials[blockIdx.x];
  if (i < n) start1[i] = ex;
  else if (i < n2) start2[i - n] = ex - (unsigned int)Etot;
}

__global__ void k_edgemlp(const float* __restrict__ ea,
                          const int* __restrict__ eidx, int ecnt,
                          const unsigned int* __restrict__ rank,
                          const unsigned int* __restrict__ start,
                          const float* __restrict__ w1, const float* __restrict__ b1,
                          const float* __restrict__ w2, const float* __restrict__ b2,
                          unsigned short* __restrict__ h3s, int* __restrict__ ssrc) {
  __shared__ float sw1[KER * 8], sb1[8], sw2[8 * WID], sb2[WID];
  int tid = threadIdx.x;
  if (tid < KER * 8) sw1[tid] = w1[tid];
  if (tid < 8) sb1[tid] = b1[tid];
  if (tid < 8 * WID) sw2[tid] = w2[tid];
  if (tid < WID) sb2[tid] = b2[tid];
  __syncthreads();
  int e = blockIdx.x * blockDim.x + tid;
  if (e >= ecnt) return;
  float a[KER];
  #pragma unroll
  for (int i = 0; i < KER; i++) a[i] = ea[e * KER + i];
  float h8[8];
  #pragma unroll
  for (int o = 0; o < 8; o++) {
    float s = sb1[o];
    #pragma unroll
    for (int i = 0; i < KER; i++) s += a[i] * sw1[i * 8 + o];
    h8[o] = fmaxf(s, 0.f);
  }
  int d = eidx[ecnt + e];
  unsigned int p = start[d] + rank[e];
  ssrc[p] = eidx[e];
  size_t base = (size_t)p * WID;
  #pragma unroll
  for (int o = 0; o < WID; o++) {
    float s = sb2[o];
    #pragma unroll
    for (int i = 0; i < 8; i++) s += h8[i] * sw2[i * WID + o];
    h3s[base + o] = f2bf(fmaxf(s, 0.f));
  }
}

__global__ void k_pack2(const float* __restrict__ w3a, const float* __restrict__ b3a,
                        unsigned short* __restrict__ oa,
                        const float* __restrict__ w3b, const float* __restrict__ b3b,
                        unsigned short* __restrict__ ob) {
  int idx = blockIdx.x * blockDim.x + threadIdx.x;
  if (idx >= 2 * WEXT_ELEMS) return;
  int which = idx >= WEXT_ELEMS;
  int id2 = which ? idx - WEXT_ELEMS : idx;
  const float* w3 = which ? w3b : w3a;
  const float* b3 = which ? b3b : b3a;
  unsigned short* outp = which ? ob : oa;
  int j = id2 & 7, l = (id2 >> 3) & 63, tt = (id2 >> 9) & 1, s = id2 >> 10;
  int p = ((l >> 4) << 3) + j;
  int o = tt * 16 + (l & 15);
  float v = (s < 32) ? w3[s * 1024 + p * 32 + o] : b3[p * 32 + o];
  outp[id2] = f2bf(v);
}

__launch_bounds__(512)
__global__ void k_msg2(const unsigned short* __restrict__ hbf,
                       const unsigned short* __restrict__ h3s1, const int* __restrict__ ssrc1,
                       int ecnt1, const unsigned short* __restrict__ w1,
                       unsigned short* __restrict__ msg1,
                       const unsigned short* __restrict__ h3s2, const int* __restrict__ ssrc2,
                       int ecnt2, const unsigned short* __restrict__ w2,
                       unsigned short* __restrict__ msg2, int B1f) {
  const unsigned short* h3s; const int* ssrc; const unsigned short* wext;
  unsigned short* msgbuf; int ecnt, blk0, nblk;
  if ((int)blockIdx.x < B1f) {
    h3s = h3s1; ssrc = ssrc1; wext = w1; msgbuf = msg1; ecnt = ecnt1;
    blk0 = blockIdx.x; nblk = B1f;
  } else {
    h3s = h3s2; ssrc = ssrc2; wext = w2; msgbuf = msg2; ecnt = ecnt2;
    blk0 = blockIdx.x - B1f; nblk = gridDim.x - B1f;
  }
  __shared__ __align__(16) unsigned short wlds[WEXT_ELEMS];
  {
    const uint4* s4 = (const uint4*)wext;
    uint4* d4 = (uint4*)wlds;
    for (int i = threadIdx.x; i < WEXT_ELEMS / 8; i += blockDim.x) d4[i] = s4[i];
  }
  __syncthreads();
  const int lane = threadIdx.x & 63;
  const int wv = threadIdx.x >> 6;
  const int nst = (ecnt + 31) >> 5;
  const int wpb = blockDim.x >> 6;
  const int nwv = nblk * wpb;
  for (int st = blk0 * wpb + wv; st < nst; st += nwv)
    msg_supertile(hbf, h3s, ssrc, ecnt, msgbuf, wlds, st, lane);
}

__global__ void k_update(const unsigned short* __restrict__ msg1,
                         const unsigned short* __restrict__ msg2,
                         const unsigned int* __restrict__ start1, const unsigned int* __restrict__ cnt1,
                         const unsigned int* __restrict__ start2, const unsigned int* __restrict__ cnt2,
                         const float* __restrict__ root1, const float* __restrict__ root2,
                         const float* __restrict__ bias1, const float* __restrict__ bias2,
                         float* __restrict__ h, unsigned short* __restrict__ hbf,
                         int last, const float* __restrict__ fc2w, const float* __restrict__ fc2b,
                         float* __restrict__ out, int n_nodes) {
  __shared__ float rs[WID * WID];
  __shared__ float bs[WID];
  __shared__ float hrow[8][WID];
  int tid = threadIdx.x;
  for (int i = tid; i < WID * WID; i += blockDim.x) rs[i] = root1[i] + root2[i];
  if (tid < WID) bs[tid] = bias1[tid] + bias2[tid];
  int o = tid & 31, nl = tid >> 5;
  int n = blockIdx.x * 8 + nl;
  bool ok = (n < n_nodes);
  hrow[nl][o] = ok ? h[(size_t)n * WID + o] : 0.f;
  __syncthreads();
  if (!ok) return;
  unsigned int b1 = start1[n], c1 = cnt1[n];
  unsigned int b2 = start2[n], c2 = cnt2[n];
  float s1 = 0.f, s2 = 0.f;
  for (unsigned int k = 0; k < c1; k++) s1 += bf2f(msg1[(size_t)(b1 + k) * WID + o]);
  for (unsigned int k = 0; k < c2; k++) s2 += bf2f(msg2[(size_t)(b2 + k) * WID + o]);
  float v = s1 / (float)(c1 ? c1 : 1u) + s2 / (float)(c2 ? c2 : 1u) + bs[o];
  #pragma unroll
  for (int i = 0; i < WID; i++) v += hrow[nl][i] * rs[i * WID + o];
  v = fmaxf(v, 0.f);
  h[(size_t)n * WID + o] = v;
  hbf[(size_t)n * WID + o] = f2bf(v);
  if (last) {
    float pv = v * fc2w[o];
    #pragma unroll
    for (int m = 16; m >= 1; m >>= 1) pv += __shfl_xor(pv, m, 32);
    if (o == 0) out[n] = pv + fc2b[0];
  }
}

extern "C" void kernel_launch(void* const* d_in, const int* in_sizes, int n_in,
                              void* d_out, int out_size, void* d_ws, size_t ws_size,
                              hipStream_t stream) {
  const float* x    = (const float*)d_in[0];
  const int*   ei   = (const int*)d_in[1];
  const float* ea   = (const float*)d_in[2];
  const int*   eib  = (const int*)d_in[3];
  const float* eab  = (const float*)d_in[4];
  const float* fc1w = (const float*)d_in[5];
  const float* fc1b = (const float*)d_in[6];
  const float* k1w1 = (const float*)d_in[7];
  const float* k1b1 = (const float*)d_in[8];
  const float* k1w2 = (const float*)d_in[9];
  const float* k1b2 = (const float*)d_in[10];
  const float* k1w3 = (const float*)d_in[11];
  const float* k1b3 = (const float*)d_in[12];
  const float* k2w1 = (const float*)d_in[13];
  const float* k2b1 = (const float*)d_in[14];
  const float* k2w2 = (const float*)d_in[15];
  const float* k2b2 = (const float*)d_in[16];
  const float* k2w3 = (const float*)d_in[17];
  const float* k2b3 = (const float*)d_in[18];
  const float* root1 = (const float*)d_in[19];
  const float* bias1 = (const float*)d_in[20];
  const float* root2 = (const float*)d_in[21];
  const float* bias2 = (const float*)d_in[22];
  const float* fc2w = (const float*)d_in[23];
  const float* fc2b = (const float*)d_in[24];
  float* out = (float*)d_out;

  const int n_nodes = in_sizes[0];
  const int E  = in_sizes[1] / 2;
  const int EB = in_sizes[3] / 2;

  char* ws = (char*)d_ws;
  size_t off = 0;
  auto alloc = [&](size_t bytes) -> void* {
    void* p = ws + off;
    off = (off + bytes + 255) & ~(size_t)255;
    return p;
  };
  unsigned short* h3s1 = (unsigned short*)alloc((size_t)E * WID * 2);
  unsigned short* h3s2 = (unsigned short*)alloc((size_t)EB * WID * 2);
  unsigned short* w1b  = (unsigned short*)alloc((size_t)WEXT_ELEMS * 2);
  unsigned short* w2b  = (unsigned short*)alloc((size_t)WEXT_ELEMS * 2);
  float* h             = (float*)alloc((size_t)n_nodes * WID * 4);
  unsigned short* hbf  = (unsigned short*)alloc((size_t)n_nodes * WID * 2);
  unsigned short* msg1 = (unsigned short*)alloc((size_t)E * WID * 2);
  unsigned short* msg2 = (unsigned short*)alloc((size_t)EB * WID * 2);
  unsigned int* cnt12  = (unsigned int*)alloc((size_t)2 * n_nodes * 4);
  unsigned int* cnt1 = cnt12;
  unsigned int* cnt2 = cnt12 + n_nodes;
  unsigned int* start1 = (unsigned int*)alloc((size_t)n_nodes * 4);
  unsigned int* start2 = (unsigned int*)alloc((size_t)n_nodes * 4);
  unsigned int* rank1  = (unsigned int*)alloc((size_t)E * 4);
  unsigned int* rank2  = (unsigned int*)alloc((size_t)EB * 4);
  int* ssrc1 = (int*)alloc((size_t)E * 4);
  int* ssrc2 = (int*)alloc((size_t)EB * 4);
  unsigned int* partials = (unsigned int*)alloc((size_t)1024 * 4);
  (void)ws_size; (void)n_in; (void)out_size;

  int B1c = (int)(((long long)NB * E) / (E + EB));
  if (B1c < 1) B1c = 1;
  if (B1c > NB - 1) B1c = NB - 1;

  MegaArgs ma;
  ma.x = x; ma.ei = ei; ma.ea = ea; ma.eib = eib; ma.eab = eab;
  ma.fc1w = fc1w; ma.fc1b = fc1b;
  ma.k1w1 = k1w1; ma.k1b1 = k1b1; ma.k1w2 = k1w2; ma.k1b2 = k1b2; ma.k1w3 = k1w3; ma.k1b3 = k1b3;
  ma.k2w1 = k2w1; ma.k2b1 = k2b1; ma.k2w2 = k2w2; ma.k2b2 = k2b2; ma.k2w3 = k2w3; ma.k2b3 = k2b3;
  ma.root1 = root1; ma.bias1 = bias1; ma.root2 = root2; ma.bias2 = bias2;
  ma.fc2w = fc2w; ma.fc2b = fc2b; ma.out = out;
  ma.h3s1 = h3s1; ma.h3s2 = h3s2; ma.w1b = w1b; ma.w2b = w2b; ma.hbf = hbf;
  ma.h = h; ma.msg1 = msg1; ma.msg2 = msg2;
  ma.cnt12 = cnt12; ma.start1 = start1; ma.start2 = start2;
  ma.rank1 = rank1; ma.rank2 = rank2; ma.partials = partials;
  ma.ssrc1 = ssrc1; ma.ssrc2 = ssrc2;
  ma.n_nodes = n_nodes; ma.E = E; ma.EB = EB; ma.B1 = B1c;

  void* kargs[] = { (void*)&ma };
  hipError_t cerr = hipLaunchCooperativeKernel(reinterpret_cast<const void*>(&k_mega),
                                               dim3(NB), dim3(NT), kargs, 0, stream);
  if (cerr == hipSuccess) return;
  (void)hipGetLastError();   // clear sticky error, fall back to multi-dispatch

  const int n2 = 2 * n_nodes;
  const int nb = (n2 + 255) / 256;
  hipMemsetAsync(cnt12, 0, (size_t)n2 * 4, stream);
  int tot = E + EB;
  k_cnt<<<(tot + 255) / 256, 256, 0, stream>>>(ei, E, eib, EB, cnt1, cnt2, rank1, rank2);
  k_scan1<<<nb, 256, 0, stream>>>(cnt12, partials, n2);
  k_scan2<<<1, 1024, 0, stream>>>(partials, nb);
  k_scan3<<<nb, 256, 0, stream>>>(cnt12, partials, start1, start2, n_nodes, E);
  k_h0<<<(n_nodes * WID + 255) / 256, 256, 0, stream>>>(x, fc1w, fc1b, h, hbf, n_nodes);
  k_edgemlp<<<(E + 255) / 256, 256, 0, stream>>>(ea, ei, E, rank1, start1,
                                                 k1w1, k1b1, k1w2, k1b2, h3s1, ssrc1);
  k_edgemlp<<<(EB + 255) / 256, 256, 0, stream>>>(eab, eib, EB, rank2, start2,
                                                  k2w1, k2b1, k2w2, k2b2, h3s2, ssrc2);
  k_pack2<<<(2 * WEXT_ELEMS + 255) / 256, 256, 0, stream>>>(k1w3, k1b3, w1b, k2w3, k2b3, w2b);

  const int GRID = 512;
  int B1f = (int)(((long long)GRID * E) / (E + EB));
  if (B1f < 1) B1f = 1;
  if (B1f > GRID - 1) B1f = GRID - 1;

  for (int t = 0; t < DEPTH; t++) {
    k_msg2<<<GRID, 512, 0, stream>>>(hbf, h3s1, ssrc1, E, w1b, msg1,
                                     h3s2, ssrc2, EB, w2b, msg2, B1f);
    int last = (t == DEPTH - 1);
    k_update<<<(n_nodes + 7) / 8, 256, 0, stream>>>(msg1, msg2, start1, cnt1, start2, cnt2,
                                                    root1, root2, bias1, bias2, h, hbf,
                                                    last, fc2w, fc2b, out, n_nodes);
  }
}

// Round 10
// 325.916 us; speedup vs baseline: 2.6208x; 2.6208x over previous
//
#include <hip/hip_runtime.h>
#include <hip/hip_bf16.h>

#define WID 32
#define KER 6
#define DEPTH 4
#define WEXT_ELEMS (33 * 2 * 64 * 8)   // steps x ntiles x lanes x 8

typedef __attribute__((ext_vector_type(8))) short bf16x8;
typedef __attribute__((ext_vector_type(4))) float f32x4;

static __device__ __forceinline__ float bf2f(unsigned short u) {
  union { unsigned int u; float f; } v; v.u = ((unsigned int)u) << 16; return v.f;
}
static __device__ __forceinline__ unsigned short f2bf(float f) {
  union { float f; unsigned int u; } v; v.f = f;
  unsigned int r = v.u + 0x7fffu + ((v.u >> 16) & 1u);
  return (unsigned short)(r >> 16);
}

// ---- fused prologue: cnt+rank | h0 | pack Wext, split by block range --
__global__ void k_pro(const int* __restrict__ ei, int E,
                      const int* __restrict__ eib, int EB,
                      unsigned int* __restrict__ cnt12, int n_nodes,
                      unsigned int* __restrict__ rank1, unsigned int* __restrict__ rank2,
                      const float* __restrict__ x, const float* __restrict__ fc1w,
                      const float* __restrict__ fc1b, float* __restrict__ h,
                      unsigned short* __restrict__ hbf,
                      const float* __restrict__ k1w3, const float* __restrict__ k1b3,
                      unsigned short* __restrict__ w1b,
                      const float* __restrict__ k2w3, const float* __restrict__ k2b3,
                      unsigned short* __restrict__ w2b,
                      int nbC, int nbH) {
  int bid = blockIdx.x, tid = threadIdx.x;
  if (bid < nbC) {
    int idx = bid * 256 + tid;
    if (idx < E) rank1[idx] = atomicAdd(&cnt12[ei[E + idx]], 1u);
    else if (idx < E + EB) { int e = idx - E; rank2[e] = atomicAdd(&cnt12[n_nodes + eib[EB + e]], 1u); }
  } else if (bid < nbC + nbH) {
    int gid = (bid - nbC) * 256 + tid;
    if (gid < n_nodes * WID) {
      int n = gid >> 5, o = gid & 31;
      float v = x[n] * fc1w[o] + fc1b[o];
      h[gid] = v; hbf[gid] = f2bf(v);
    }
  } else {
    int idx = (bid - nbC - nbH) * 256 + tid;
    if (idx < 2 * WEXT_ELEMS) {
      int which = idx >= WEXT_ELEMS;
      int id2 = which ? idx - WEXT_ELEMS : idx;
      const float* w3 = which ? k2w3 : k1w3;
      const float* b3 = which ? k2b3 : k1b3;
      unsigned short* outp = which ? w2b : w1b;
      int j = id2 & 7, l = (id2 >> 3) & 63, tt = (id2 >> 9) & 1, s = id2 >> 10;
      int p = ((l >> 4) << 3) + j;    // within-step K position = i (h index)
      int o = tt * 16 + (l & 15);     // output channel
      float v = (s < 32) ? w3[s * 1024 + p * 32 + o] : b3[p * 32 + o];
      outp[id2] = f2bf(v);
    }
  }
}

// ------- scan phase 1: per-block (256) sums over cnt1||cnt2 -----------
__global__ void k_scan1(const unsigned int* __restrict__ cnt, unsigned int* __restrict__ partials,
                        int n2) {
  __shared__ unsigned int s[256];
  int t = threadIdx.x;
  int i = blockIdx.x * 256 + t;
  unsigned int v = (i < n2) ? cnt[i] : 0u;
  s[t] = v;
  __syncthreads();
  for (int d = 128; d > 0; d >>= 1) {
    if (t < d) s[t] += s[t + d];
    __syncthreads();
  }
  if (t == 0) partials[blockIdx.x] = s[0];
}

// ------- scan phase 2: exclusive scan of block partials (1 block) -----
__global__ void k_scan2(unsigned int* __restrict__ partials, int nb) {
  __shared__ unsigned int s[1024];
  int t = threadIdx.x;
  unsigned int v = (t < nb) ? partials[t] : 0u;
  s[t] = v;
  __syncthreads();
  for (int d = 1; d < 1024; d <<= 1) {
    unsigned int u = (t >= d) ? s[t - d] : 0u;
    __syncthreads();
    s[t] += u;
    __syncthreads();
  }
  if (t < nb) partials[t] = s[t] - v;   // exclusive
}

// ------- scan phase 3: block-local exclusive scan + offset ------------
__global__ void k_scan3(const unsigned int* __restrict__ cnt, const unsigned int* __restrict__ partials,
                        unsigned int* __restrict__ start1, unsigned int* __restrict__ start2,
                        int n, int Etot) {
  __shared__ unsigned int s[256];
  int t = threadIdx.x;
  int i = blockIdx.x * 256 + t;
  int n2 = 2 * n;
  unsigned int v = (i < n2) ? cnt[i] : 0u;
  s[t] = v;
  __syncthreads();
  for (int d = 1; d < 256; d <<= 1) {
    unsigned int u = (t >= d) ? s[t - d] : 0u;
    __syncthreads();
    s[t] += u;
    __syncthreads();
  }
  unsigned int ex = s[t] - v + partials[blockIdx.x];
  if (i < n) start1[i] = ex;
  else if (i < n2) start2[i - n] = ex - (unsigned int)Etot;
}

// ---- fused edge MLP (both sets, role-split): ea(6)->8->32, scatter ----
__global__ void k_emlp2(const float* __restrict__ ea1, const int* __restrict__ ei, int E,
                        const unsigned int* __restrict__ rank1, const unsigned int* __restrict__ start1,
                        const float* __restrict__ k1w1, const float* __restrict__ k1b1,
                        const float* __restrict__ k1w2, const float* __restrict__ k1b2,
                        unsigned short* __restrict__ h3s1, int* __restrict__ ssrc1,
                        const float* __restrict__ ea2, const int* __restrict__ eib, int EB,
                        const unsigned int* __restrict__ rank2, const unsigned int* __restrict__ start2,
                        const float* __restrict__ k2w1, const float* __restrict__ k2b1,
                        const float* __restrict__ k2w2, const float* __restrict__ k2b2,
                        unsigned short* __restrict__ h3s2, int* __restrict__ ssrc2,
                        int nbE) {
  bool role1 = (int)blockIdx.x < nbE;
  const float* ea  = role1 ? ea1 : ea2;
  const int* eidx  = role1 ? ei : eib;
  int ecnt         = role1 ? E : EB;
  const unsigned int* rank  = role1 ? rank1 : rank2;
  const unsigned int* start = role1 ? start1 : start2;
  const float* w1 = role1 ? k1w1 : k2w1;
  const float* b1 = role1 ? k1b1 : k2b1;
  const float* w2 = role1 ? k1w2 : k2w2;
  const float* b2 = role1 ? k1b2 : k2b2;
  unsigned short* h3s = role1 ? h3s1 : h3s2;
  int* ssrc = role1 ? ssrc1 : ssrc2;
  int blk0 = role1 ? blockIdx.x : blockIdx.x - nbE;

  __shared__ float sw1[KER * 8], sb1[8], sw2[8 * WID], sb2[WID];
  int tid = threadIdx.x;
  if (tid < KER * 8) sw1[tid] = w1[tid];
  if (tid < 8) sb1[tid] = b1[tid];
  if (tid < 8 * WID) sw2[tid] = w2[tid];
  if (tid < WID) sb2[tid] = b2[tid];
  __syncthreads();
  int e = blk0 * 256 + tid;
  if (e >= ecnt) return;
  float a[KER];
  #pragma unroll
  for (int i = 0; i < KER; i++) a[i] = ea[e * KER + i];
  float h8[8];
  #pragma unroll
  for (int o = 0; o < 8; o++) {
    float s = sb1[o];
    #pragma unroll
    for (int i = 0; i < KER; i++) s += a[i] * sw1[i * 8 + o];
    h8[o] = fmaxf(s, 0.f);
  }
  int d = eidx[ecnt + e];
  unsigned int p = start[d] + rank[e];
  ssrc[p] = eidx[e];
  // compute 32 outputs, pack pairs to bf16 words, 4x uint4 stores
  unsigned int words[16];
  #pragma unroll
  for (int m = 0; m < 16; m++) {
    float s0 = sb2[2 * m], s1 = sb2[2 * m + 1];
    #pragma unroll
    for (int i = 0; i < 8; i++) {
      s0 += h8[i] * sw2[i * WID + 2 * m];
      s1 += h8[i] * sw2[i * WID + 2 * m + 1];
    }
    words[m] = (unsigned int)f2bf(fmaxf(s0, 0.f)) | ((unsigned int)f2bf(fmaxf(s1, 0.f)) << 16);
  }
  uint4* dst = (uint4*)(h3s + (size_t)p * WID);
  dst[0] = make_uint4(words[0], words[1], words[2], words[3]);
  dst[1] = make_uint4(words[4], words[5], words[6], words[7]);
  dst[2] = make_uint4(words[8], words[9], words[10], words[11]);
  dst[3] = make_uint4(words[12], words[13], words[14], words[15]);
}

// ---- message kernel (round-5 PROVEN version): 16 edges/wave-iter -----
// z[e, kk=kh*32+i] = h_src[e][i]*h3[e][kh]; msg = [z ; h_src] @ [Wf ; B3]
__launch_bounds__(512)
__global__ void k_msg2(const unsigned short* __restrict__ hbf,
                       const unsigned short* __restrict__ h3s1, const int* __restrict__ ssrc1,
                       int ecnt1, const unsigned short* __restrict__ w1,
                       unsigned short* __restrict__ msg1,
                       const unsigned short* __restrict__ h3s2, const int* __restrict__ ssrc2,
                       int ecnt2, const unsigned short* __restrict__ w2,
                       unsigned short* __restrict__ msg2, int B1) {
  const unsigned short* h3s; const int* ssrc; const unsigned short* wext;
  unsigned short* msgbuf; int ecnt, blk0, nblk;
  if ((int)blockIdx.x < B1) {
    h3s = h3s1; ssrc = ssrc1; wext = w1; msgbuf = msg1; ecnt = ecnt1;
    blk0 = blockIdx.x; nblk = B1;
  } else {
    h3s = h3s2; ssrc = ssrc2; wext = w2; msgbuf = msg2; ecnt = ecnt2;
    blk0 = blockIdx.x - B1; nblk = gridDim.x - B1;
  }
  __shared__ __align__(16) unsigned short wlds[WEXT_ELEMS];   // 67584 B
  {
    const uint4* s4 = (const uint4*)wext;
    uint4* d4 = (uint4*)wlds;
    for (int i = threadIdx.x; i < WEXT_ELEMS / 8; i += blockDim.x) d4[i] = s4[i];
  }
  __syncthreads();
  const int lane = threadIdx.x & 63;
  const int wv = threadIdx.x >> 6;
  const int g = lane >> 4, eo = lane & 15;
  const int ntile = (ecnt + 15) >> 4;
  const int wpb = blockDim.x >> 6;
  const int nwv = nblk * wpb;
  for (int tile = blk0 * wpb + wv; tile < ntile; tile += nwv) {
    const int e = min((tile << 4) + eo, ecnt - 1);
    const int srcn = ssrc[e];
    // full h3 row (32 bf16), linear read in sorted order
    const uint4* h3p = (const uint4*)(h3s + (size_t)e * WID);
    uint4 q0 = h3p[0], q1 = h3p[1], q2 = h3p[2], q3 = h3p[3];
    unsigned int h3w[16];
    h3w[0]=q0.x; h3w[1]=q0.y; h3w[2]=q0.z; h3w[3]=q0.w;
    h3w[4]=q1.x; h3w[5]=q1.y; h3w[6]=q1.z; h3w[7]=q1.w;
    h3w[8]=q2.x; h3w[9]=q2.y; h3w[10]=q2.z; h3w[11]=q2.w;
    h3w[12]=q3.x; h3w[13]=q3.y; h3w[14]=q3.z; h3w[15]=q3.w;
    // h_src fragment: 8 bf16 at positions g*8..g*8+7 (gather, L2-resident)
    uint4 hq = *(const uint4*)(hbf + (size_t)srcn * WID + g * 8);
    bf16x8 hsv = __builtin_bit_cast(bf16x8, hq);
    float hsf[8];
    #pragma unroll
    for (int j = 0; j < 8; j++) hsf[j] = bf2f((unsigned short)hsv[j]);
    f32x4 acc0 = {0.f, 0.f, 0.f, 0.f};
    f32x4 acc1 = {0.f, 0.f, 0.f, 0.f};
    #pragma unroll
    for (int s = 0; s < 32; s++) {
      unsigned int wrd = h3w[s >> 1];
      unsigned int fb = (s & 1) ? (wrd & 0xffff0000u) : (wrd << 16);
      float h3f = __builtin_bit_cast(float, fb);
      float p0 = h3f * hsf[0], p1 = h3f * hsf[1], p2 = h3f * hsf[2], p3 = h3f * hsf[3];
      float p4 = h3f * hsf[4], p5 = h3f * hsf[5], p6 = h3f * hsf[6], p7 = h3f * hsf[7];
      uint4 aw;
      asm("v_cvt_pk_bf16_f32 %0, %1, %2" : "=v"(aw.x) : "v"(p0), "v"(p1));
      asm("v_cvt_pk_bf16_f32 %0, %1, %2" : "=v"(aw.y) : "v"(p2), "v"(p3));
      asm("v_cvt_pk_bf16_f32 %0, %1, %2" : "=v"(aw.z) : "v"(p4), "v"(p5));
      asm("v_cvt_pk_bf16_f32 %0, %1, %2" : "=v"(aw.w) : "v"(p6), "v"(p7));
      bf16x8 af = __builtin_bit_cast(bf16x8, aw);
      bf16x8 b0 = *(const bf16x8*)&wlds[((s * 2 + 0) * 64 + lane) * 8];
      bf16x8 b1 = *(const bf16x8*)&wlds[((s * 2 + 1) * 64 + lane) * 8];
      acc0 = __builtin_amdgcn_mfma_f32_16x16x32_bf16(af, b0, acc0, 0, 0, 0);
      acc1 = __builtin_amdgcn_mfma_f32_16x16x32_bf16(af, b1, acc1, 0, 0, 0);
    }
    { // step 32: bias rows, A = raw h_src fragment
      bf16x8 b0 = *(const bf16x8*)&wlds[((32 * 2 + 0) * 64 + lane) * 8];
      bf16x8 b1 = *(const bf16x8*)&wlds[((32 * 2 + 1) * 64 + lane) * 8];
      acc0 = __builtin_amdgcn_mfma_f32_16x16x32_bf16(hsv, b0, acc0, 0, 0, 0);
      acc1 = __builtin_amdgcn_mfma_f32_16x16x32_bf16(hsv, b1, acc1, 0, 0, 0);
    }
    // D layout (m89): col = lane&15 (channel), row = (lane>>4)*4+r (edge slot)
    #pragma unroll
    for (int r = 0; r < 4; r++) {
      int oe = (tile << 4) + g * 4 + r;
      if (oe < ecnt) {
        msgbuf[(size_t)oe * WID + eo]      = f2bf(acc0[r]);
        msgbuf[(size_t)oe * WID + 16 + eo] = f2bf(acc1[r]);
      }
    }
  }
}

// ---- node update: segmented mean over sorted msgs + h@(root)+bias, ReLU
__global__ void k_update(const unsigned short* __restrict__ msg1,
                         const unsigned short* __restrict__ msg2,
                         const unsigned int* __restrict__ start1, const unsigned int* __restrict__ cnt1,
                         const unsigned int* __restrict__ start2, const unsigned int* __restrict__ cnt2,
                         const float* __restrict__ root1, const float* __restrict__ root2,
                         const float* __restrict__ bias1, const float* __restrict__ bias2,
                         float* __restrict__ h, unsigned short* __restrict__ hbf,
                         int last, const float* __restrict__ fc2w, const float* __restrict__ fc2b,
                         float* __restrict__ out, int n_nodes) {
  __shared__ float rs[WID * WID];
  __shared__ float bs[WID];
  __shared__ float hrow[8][WID];
  int tid = threadIdx.x;
  for (int i = tid; i < WID * WID; i += blockDim.x) rs[i] = root1[i] + root2[i];
  if (tid < WID) bs[tid] = bias1[tid] + bias2[tid];
  int o = tid & 31, nl = tid >> 5;
  int n = blockIdx.x * 8 + nl;
  bool ok = (n < n_nodes);
  hrow[nl][o] = ok ? h[(size_t)n * WID + o] : 0.f;
  __syncthreads();
  if (!ok) return;
  unsigned int b1 = start1[n], c1 = cnt1[n];
  unsigned int b2 = start2[n], c2 = cnt2[n];
  float s1 = 0.f, s2 = 0.f;
  for (unsigned int k = 0; k < c1; k++) s1 += bf2f(msg1[(size_t)(b1 + k) * WID + o]);
  for (unsigned int k = 0; k < c2; k++) s2 += bf2f(msg2[(size_t)(b2 + k) * WID + o]);
  float v = s1 / (float)(c1 ? c1 : 1u) + s2 / (float)(c2 ? c2 : 1u) + bs[o];
  #pragma unroll
  for (int i = 0; i < WID; i++) v += hrow[nl][i] * rs[i * WID + o];
  v = fmaxf(v, 0.f);
  h[(size_t)n * WID + o] = v;
  hbf[(size_t)n * WID + o] = f2bf(v);
  if (last) {
    float pv = v * fc2w[o];
    #pragma unroll
    for (int m = 16; m >= 1; m >>= 1) pv += __shfl_xor(pv, m, 32);
    if (o == 0) out[n] = pv + fc2b[0];
  }
}

extern "C" void kernel_launch(void* const* d_in, const int* in_sizes, int n_in,
                              void* d_out, int out_size, void* d_ws, size_t ws_size,
                              hipStream_t stream) {
  const float* x    = (const float*)d_in[0];
  const int*   ei   = (const int*)d_in[1];
  const float* ea   = (const float*)d_in[2];
  const int*   eib  = (const int*)d_in[3];
  const float* eab  = (const float*)d_in[4];
  const float* fc1w = (const float*)d_in[5];
  const float* fc1b = (const float*)d_in[6];
  const float* k1w1 = (const float*)d_in[7];
  const float* k1b1 = (const float*)d_in[8];
  const float* k1w2 = (const float*)d_in[9];
  const float* k1b2 = (const float*)d_in[10];
  const float* k1w3 = (const float*)d_in[11];
  const float* k1b3 = (const float*)d_in[12];
  const float* k2w1 = (const float*)d_in[13];
  const float* k2b1 = (const float*)d_in[14];
  const float* k2w2 = (const float*)d_in[15];
  const float* k2b2 = (const float*)d_in[16];
  const float* k2w3 = (const float*)d_in[17];
  const float* k2b3 = (const float*)d_in[18];
  const float* root1 = (const float*)d_in[19];
  const float* bias1 = (const float*)d_in[20];
  const float* root2 = (const float*)d_in[21];
  const float* bias2 = (const float*)d_in[22];
  const float* fc2w = (const float*)d_in[23];
  const float* fc2b = (const float*)d_in[24];
  float* out = (float*)d_out;

  const int n_nodes = in_sizes[0];
  const int E  = in_sizes[1] / 2;
  const int EB = in_sizes[3] / 2;

  char* ws = (char*)d_ws;
  size_t off = 0;
  auto alloc = [&](size_t bytes) -> void* {
    void* p = ws + off;
    off = (off + bytes + 255) & ~(size_t)255;
    return p;
  };
  unsigned short* h3s1 = (unsigned short*)alloc((size_t)E * WID * 2);
  unsigned short* h3s2 = (unsigned short*)alloc((size_t)EB * WID * 2);
  unsigned short* w1b  = (unsigned short*)alloc((size_t)WEXT_ELEMS * 2);
  unsigned short* w2b  = (unsigned short*)alloc((size_t)WEXT_ELEMS * 2);
  float* h             = (float*)alloc((size_t)n_nodes * WID * 4);
  unsigned short* hbf  = (unsigned short*)alloc((size_t)n_nodes * WID * 2);
  unsigned short* msg1 = (unsigned short*)alloc((size_t)E * WID * 2);
  unsigned short* msg2 = (unsigned short*)alloc((size_t)EB * WID * 2);
  unsigned int* cnt12  = (unsigned int*)alloc((size_t)2 * n_nodes * 4);  // cnt1||cnt2 contiguous
  unsigned int* cnt1 = cnt12;
  unsigned int* cnt2 = cnt12 + n_nodes;
  unsigned int* start1 = (unsigned int*)alloc((size_t)n_nodes * 4);
  unsigned int* start2 = (unsigned int*)alloc((size_t)n_nodes * 4);
  unsigned int* rank1  = (unsigned int*)alloc((size_t)E * 4);
  unsigned int* rank2  = (unsigned int*)alloc((size_t)EB * 4);
  int* ssrc1 = (int*)alloc((size_t)E * 4);
  int* ssrc2 = (int*)alloc((size_t)EB * 4);
  unsigned int* partials = (unsigned int*)alloc((size_t)1024 * 4);
  (void)ws_size; (void)n_in; (void)out_size;

  const int n2 = 2 * n_nodes;
  const int nb = (n2 + 255) / 256;      // scan blocks (391 for N=50000)
  const int nbC = (E + EB + 255) / 256;
  const int nbH = (n_nodes * WID + 255) / 256;
  const int nbP = (2 * WEXT_ELEMS + 255) / 256;
  const int nbE = (E + 255) / 256;
  const int nbEB = (EB + 255) / 256;

  // ---- prologue: fused cnt/h0/pack, then scan, then fused edge MLP ----
  hipMemsetAsync(cnt12, 0, (size_t)n2 * 4, stream);
  k_pro<<<nbC + nbH + nbP, 256, 0, stream>>>(ei, E, eib, EB, cnt12, n_nodes, rank1, rank2,
                                             x, fc1w, fc1b, h, hbf,
                                             k1w3, k1b3, w1b, k2w3, k2b3, w2b, nbC, nbH);
  k_scan1<<<nb, 256, 0, stream>>>(cnt12, partials, n2);
  k_scan2<<<1, 1024, 0, stream>>>(partials, nb);
  k_scan3<<<nb, 256, 0, stream>>>(cnt12, partials, start1, start2, n_nodes, E);
  k_emlp2<<<nbE + nbEB, 256, 0, stream>>>(ea, ei, E, rank1, start1, k1w1, k1b1, k1w2, k1b2, h3s1, ssrc1,
                                          eab, eib, EB, rank2, start2, k2w1, k2b1, k2w2, k2b2, h3s2, ssrc2,
                                          nbE);

  const int GRID = 512;
  int B1 = (int)(((long long)GRID * E) / (E + EB));
  if (B1 < 1) B1 = 1;
  if (B1 > GRID - 1) B1 = GRID - 1;

  for (int t = 0; t < DEPTH; t++) {
    k_msg2<<<GRID, 512, 0, stream>>>(hbf, h3s1, ssrc1, E, w1b, msg1,
                                     h3s2, ssrc2, EB, w2b, msg2, B1);
    int last = (t == DEPTH - 1);
    k_update<<<(n_nodes + 7) / 8, 256, 0, stream>>>(msg1, msg2, start1, cnt1, start2, cnt2,
                                                    root1, root2, bias1, bias2, h, hbf,
                                                    last, fc2w, fc2b, out, n_nodes);
  }
}

// Round 11
// 297.110 us; speedup vs baseline: 2.8749x; 1.0970x over previous
//
#include <hip/hip_runtime.h>
#include <hip/hip_bf16.h>

#define WID 32
#define KER 6
#define DEPTH 4
#define W32_ELEMS (66 * 64 * 8)   // steps(64+2 bias) x lanes x 8 = 33792 bf16 = 67584 B

typedef __attribute__((ext_vector_type(8))) short bf16x8;
typedef __attribute__((ext_vector_type(4))) float f32x4;
typedef __attribute__((ext_vector_type(16))) float f32x16;

static __device__ __forceinline__ float bf2f(unsigned short u) {
  union { unsigned int u; float f; } v; v.u = ((unsigned int)u) << 16; return v.f;
}
static __device__ __forceinline__ unsigned short f2bf(float f) {
  union { float f; unsigned int u; } v; v.f = f;
  unsigned int r = v.u + 0x7fffu + ((v.u >> 16) & 1u);
  return (unsigned short)(r >> 16);
}

// ---- fused prologue: cnt+rank | h0 | pack Wext(32x32 layout) ---------
__global__ void k_pro(const int* __restrict__ ei, int E,
                      const int* __restrict__ eib, int EB,
                      unsigned int* __restrict__ cnt12, int n_nodes,
                      unsigned int* __restrict__ rank1, unsigned int* __restrict__ rank2,
                      const float* __restrict__ x, const float* __restrict__ fc1w,
                      const float* __restrict__ fc1b, float* __restrict__ h,
                      unsigned short* __restrict__ hbf,
                      const float* __restrict__ k1w3, const float* __restrict__ k1b3,
                      unsigned short* __restrict__ w1b,
                      const float* __restrict__ k2w3, const float* __restrict__ k2b3,
                      unsigned short* __restrict__ w2b,
                      int nbC, int nbH) {
  int bid = blockIdx.x, tid = threadIdx.x;
  if (bid < nbC) {
    int idx = bid * 256 + tid;
    if (idx < E) rank1[idx] = atomicAdd(&cnt12[ei[E + idx]], 1u);
    else if (idx < E + EB) { int e = idx - E; rank2[e] = atomicAdd(&cnt12[n_nodes + eib[EB + e]], 1u); }
  } else if (bid < nbC + nbH) {
    int gid = (bid - nbC) * 256 + tid;
    if (gid < n_nodes * WID) {
      int n = gid >> 5, o = gid & 31;
      float v = x[n] * fc1w[o] + fc1b[o];
      h[gid] = v; hbf[gid] = f2bf(v);
    }
  } else {
    int idx = (bid - nbC - nbH) * 256 + tid;
    if (idx < 2 * W32_ELEMS) {
      int which = idx >= W32_ELEMS;
      int id2 = which ? idx - W32_ELEMS : idx;
      const float* w3 = which ? k2w3 : k1w3;
      const float* b3 = which ? k2b3 : k1b3;
      unsigned short* outp = which ? w2b : w1b;
      // B-fragment for mfma_32x32x16: lane l holds k=((l>>5)<<3)+j, col=l&31
      int j = id2 & 7, l = (id2 >> 3) & 63, s = id2 >> 9;   // s in [0,66)
      int o = l & 31;
      float v;
      if (s < 64) {
        int m = s >> 1;                                   // kh (h3 index)
        int i = ((s & 1) << 4) + ((l >> 5) << 3) + j;     // hsrc index
        v = w3[m * 1024 + i * 32 + o];
      } else {
        int t2 = s - 64;
        int i = (t2 << 4) + ((l >> 5) << 3) + j;
        v = b3[i * 32 + o];
      }
      outp[id2] = f2bf(v);
    }
  }
}

// ------- scan phase 1: per-block (256) sums over cnt1||cnt2 -----------
__global__ void k_scan1(const unsigned int* __restrict__ cnt, unsigned int* __restrict__ partials,
                        int n2) {
  __shared__ unsigned int s[256];
  int t = threadIdx.x;
  int i = blockIdx.x * 256 + t;
  unsigned int v = (i < n2) ? cnt[i] : 0u;
  s[t] = v;
  __syncthreads();
  for (int d = 128; d > 0; d >>= 1) {
    if (t < d) s[t] += s[t + d];
    __syncthreads();
  }
  if (t == 0) partials[blockIdx.x] = s[0];
}

// ------- scan phase 2: exclusive scan of block partials (1 block) -----
__global__ void k_scan2(unsigned int* __restrict__ partials, int nb) {
  __shared__ unsigned int s[1024];
  int t = threadIdx.x;
  unsigned int v = (t < nb) ? partials[t] : 0u;
  s[t] = v;
  __syncthreads();
  for (int d = 1; d < 1024; d <<= 1) {
    unsigned int u = (t >= d) ? s[t - d] : 0u;
    __syncthreads();
    s[t] += u;
    __syncthreads();
  }
  if (t < nb) partials[t] = s[t] - v;   // exclusive
}

// ------- scan phase 3: block-local exclusive scan + offset ------------
__global__ void k_scan3(const unsigned int* __restrict__ cnt, const unsigned int* __restrict__ partials,
                        unsigned int* __restrict__ start1, unsigned int* __restrict__ start2,
                        int n, int Etot) {
  __shared__ unsigned int s[256];
  int t = threadIdx.x;
  int i = blockIdx.x * 256 + t;
  int n2 = 2 * n;
  unsigned int v = (i < n2) ? cnt[i] : 0u;
  s[t] = v;
  __syncthreads();
  for (int d = 1; d < 256; d <<= 1) {
    unsigned int u = (t >= d) ? s[t - d] : 0u;
    __syncthreads();
    s[t] += u;
    __syncthreads();
  }
  unsigned int ex = s[t] - v + partials[blockIdx.x];
  if (i < n) start1[i] = ex;
  else if (i < n2) start2[i - n] = ex - (unsigned int)Etot;
}

// ---- fused edge MLP (both sets, role-split): ea(6)->8->32, scatter ----
__global__ void k_emlp2(const float* __restrict__ ea1, const int* __restrict__ ei, int E,
                        const unsigned int* __restrict__ rank1, const unsigned int* __restrict__ start1,
                        const float* __restrict__ k1w1, const float* __restrict__ k1b1,
                        const float* __restrict__ k1w2, const float* __restrict__ k1b2,
                        unsigned short* __restrict__ h3s1, int* __restrict__ ssrc1,
                        const float* __restrict__ ea2, const int* __restrict__ eib, int EB,
                        const unsigned int* __restrict__ rank2, const unsigned int* __restrict__ start2,
                        const float* __restrict__ k2w1, const float* __restrict__ k2b1,
                        const float* __restrict__ k2w2, const float* __restrict__ k2b2,
                        unsigned short* __restrict__ h3s2, int* __restrict__ ssrc2,
                        int nbE) {
  bool role1 = (int)blockIdx.x < nbE;
  const float* ea  = role1 ? ea1 : ea2;
  const int* eidx  = role1 ? ei : eib;
  int ecnt         = role1 ? E : EB;
  const unsigned int* rank  = role1 ? rank1 : rank2;
  const unsigned int* start = role1 ? start1 : start2;
  const float* w1 = role1 ? k1w1 : k2w1;
  const float* b1 = role1 ? k1b1 : k2b1;
  const float* w2 = role1 ? k1w2 : k2w2;
  const float* b2 = role1 ? k1b2 : k2b2;
  unsigned short* h3s = role1 ? h3s1 : h3s2;
  int* ssrc = role1 ? ssrc1 : ssrc2;
  int blk0 = role1 ? blockIdx.x : blockIdx.x - nbE;

  __shared__ float sw1[KER * 8], sb1[8], sw2[8 * WID], sb2[WID];
  int tid = threadIdx.x;
  if (tid < KER * 8) sw1[tid] = w1[tid];
  if (tid < 8) sb1[tid] = b1[tid];
  if (tid < 8 * WID) sw2[tid] = w2[tid];
  if (tid < WID) sb2[tid] = b2[tid];
  __syncthreads();
  int e = blk0 * 256 + tid;
  if (e >= ecnt) return;
  float a[KER];
  #pragma unroll
  for (int i = 0; i < KER; i++) a[i] = ea[e * KER + i];
  float h8[8];
  #pragma unroll
  for (int o = 0; o < 8; o++) {
    float s = sb1[o];
    #pragma unroll
    for (int i = 0; i < KER; i++) s += a[i] * sw1[i * 8 + o];
    h8[o] = fmaxf(s, 0.f);
  }
  int d = eidx[ecnt + e];
  unsigned int p = start[d] + rank[e];
  ssrc[p] = eidx[e];
  unsigned int words[16];
  #pragma unroll
  for (int m = 0; m < 16; m++) {
    float s0 = sb2[2 * m], s1 = sb2[2 * m + 1];
    #pragma unroll
    for (int i = 0; i < 8; i++) {
      s0 += h8[i] * sw2[i * WID + 2 * m];
      s1 += h8[i] * sw2[i * WID + 2 * m + 1];
    }
    words[m] = (unsigned int)f2bf(fmaxf(s0, 0.f)) | ((unsigned int)f2bf(fmaxf(s1, 0.f)) << 16);
  }
  uint4* dst = (uint4*)(h3s + (size_t)p * WID);
  dst[0] = make_uint4(words[0], words[1], words[2], words[3]);
  dst[1] = make_uint4(words[4], words[5], words[6], words[7]);
  dst[2] = make_uint4(words[8], words[9], words[10], words[11]);
  dst[3] = make_uint4(words[12], words[13], words[14], words[15]);
}

// ---- message kernel: 32x32x16 MFMA, 32 edges/wave-iter, 1 acc set ----
// z[e, kk=kh*32+i] = h_src[e][i]*h3[e][kh]; msg = [z ; h_src] @ [Wf ; B3]
__launch_bounds__(512)
__global__ void k_msg32(const unsigned short* __restrict__ hbf,
                        const unsigned short* __restrict__ h3s1, const int* __restrict__ ssrc1,
                        int ecnt1, const unsigned short* __restrict__ w1,
                        unsigned short* __restrict__ msg1,
                        const unsigned short* __restrict__ h3s2, const int* __restrict__ ssrc2,
                        int ecnt2, const unsigned short* __restrict__ w2,
                        unsigned short* __restrict__ msg2, int B1) {
  const unsigned short* h3s; const int* ssrc; const unsigned short* wext;
  unsigned short* msgbuf; int ecnt, blk0, nblk;
  if ((int)blockIdx.x < B1) {
    h3s = h3s1; ssrc = ssrc1; wext = w1; msgbuf = msg1; ecnt = ecnt1;
    blk0 = blockIdx.x; nblk = B1;
  } else {
    h3s = h3s2; ssrc = ssrc2; wext = w2; msgbuf = msg2; ecnt = ecnt2;
    blk0 = blockIdx.x - B1; nblk = gridDim.x - B1;
  }
  __shared__ __align__(16) unsigned short wlds[W32_ELEMS];   // 67584 B
  {
    const uint4* s4 = (const uint4*)wext;
    uint4* d4 = (uint4*)wlds;
    for (int i = threadIdx.x; i < W32_ELEMS / 8; i += blockDim.x) d4[i] = s4[i];
  }
  __syncthreads();
  const int lane = threadIdx.x & 63;
  const int wvid = threadIdx.x >> 6;
  const int col = lane & 31, kg = lane >> 5;     // edge slot / k-group
  const int base = kg << 3;
  const int ntile = (ecnt + 31) >> 5;            // 32 edges per tile
  const int wpb = blockDim.x >> 6;
  const int nwv = nblk * wpb;
  for (int tile = blk0 * wpb + wvid; tile < ntile; tile += nwv) {
    const int e = min((tile << 5) + col, ecnt - 1);
    const int srcn = ssrc[e];
    // full h3 row (32 bf16) for this lane's edge, linear in sorted order
    const uint4* h3p = (const uint4*)(h3s + (size_t)e * WID);
    uint4 q0 = h3p[0], q1 = h3p[1], q2 = h3p[2], q3 = h3p[3];
    unsigned int h3w[16];
    h3w[0]=q0.x; h3w[1]=q0.y; h3w[2]=q0.z; h3w[3]=q0.w;
    h3w[4]=q1.x; h3w[5]=q1.y; h3w[6]=q1.z; h3w[7]=q1.w;
    h3w[8]=q2.x; h3w[9]=q2.y; h3w[10]=q2.z; h3w[11]=q2.w;
    h3w[12]=q3.x; h3w[13]=q3.y; h3w[14]=q3.z; h3w[15]=q3.w;
    // h_src fragments: i = base..base+7 (A-half) and 16+base..16+base+7 (B-half)
    uint4 hqA = *(const uint4*)(hbf + (size_t)srcn * WID + base);
    uint4 hqB = *(const uint4*)(hbf + (size_t)srcn * WID + 16 + base);
    bf16x8 hsvA = __builtin_bit_cast(bf16x8, hqA);
    bf16x8 hsvB = __builtin_bit_cast(bf16x8, hqB);
    float hfA[8], hfB[8];
    #pragma unroll
    for (int j = 0; j < 8; j++) { hfA[j] = bf2f((unsigned short)hsvA[j]); hfB[j] = bf2f((unsigned short)hsvB[j]); }
    f32x16 acc = {0.f,0.f,0.f,0.f,0.f,0.f,0.f,0.f,0.f,0.f,0.f,0.f,0.f,0.f,0.f,0.f};
    #pragma unroll
    for (int sp = 0; sp < 32; sp++) {          // kh = sp; two K=16 steps per sp
      unsigned int wrd = h3w[sp >> 1];
      unsigned int fb = (sp & 1) ? (wrd & 0xffff0000u) : (wrd << 16);
      float h3f = __builtin_bit_cast(float, fb);
      // even step: i = base+j
      float p0 = h3f*hfA[0], p1 = h3f*hfA[1], p2 = h3f*hfA[2], p3 = h3f*hfA[3];
      float p4 = h3f*hfA[4], p5 = h3f*hfA[5], p6 = h3f*hfA[6], p7 = h3f*hfA[7];
      uint4 aw;
      asm("v_cvt_pk_bf16_f32 %0, %1, %2" : "=v"(aw.x) : "v"(p0), "v"(p1));
      asm("v_cvt_pk_bf16_f32 %0, %1, %2" : "=v"(aw.y) : "v"(p2), "v"(p3));
      asm("v_cvt_pk_bf16_f32 %0, %1, %2" : "=v"(aw.z) : "v"(p4), "v"(p5));
      asm("v_cvt_pk_bf16_f32 %0, %1, %2" : "=v"(aw.w) : "v"(p6), "v"(p7));
      bf16x8 af = __builtin_bit_cast(bf16x8, aw);
      bf16x8 b0 = *(const bf16x8*)&wlds[(((sp * 2 + 0) * 64) + lane) * 8];
      acc = __builtin_amdgcn_mfma_f32_32x32x16_bf16(af, b0, acc, 0, 0, 0);
      // odd step: i = 16+base+j
      float q0f = h3f*hfB[0], q1f = h3f*hfB[1], q2f = h3f*hfB[2], q3f = h3f*hfB[3];
      float q4f = h3f*hfB[4], q5f = h3f*hfB[5], q6f = h3f*hfB[6], q7f = h3f*hfB[7];
      uint4 aw2;
      asm("v_cvt_pk_bf16_f32 %0, %1, %2" : "=v"(aw2.x) : "v"(q0f), "v"(q1f));
      asm("v_cvt_pk_bf16_f32 %0, %1, %2" : "=v"(aw2.y) : "v"(q2f), "v"(q3f));
      asm("v_cvt_pk_bf16_f32 %0, %1, %2" : "=v"(aw2.z) : "v"(q4f), "v"(q5f));
      asm("v_cvt_pk_bf16_f32 %0, %1, %2" : "=v"(aw2.w) : "v"(q6f), "v"(q7f));
      bf16x8 af2 = __builtin_bit_cast(bf16x8, aw2);
      bf16x8 b1 = *(const bf16x8*)&wlds[(((sp * 2 + 1) * 64) + lane) * 8];
      acc = __builtin_amdgcn_mfma_f32_32x32x16_bf16(af2, b1, acc, 0, 0, 0);
    }
    { // bias steps 64,65: A = raw h_src fragments
      bf16x8 b64 = *(const bf16x8*)&wlds[((64 * 64) + lane) * 8];
      bf16x8 b65 = *(const bf16x8*)&wlds[((65 * 64) + lane) * 8];
      acc = __builtin_amdgcn_mfma_f32_32x32x16_bf16(hsvA, b64, acc, 0, 0, 0);
      acc = __builtin_amdgcn_mfma_f32_32x32x16_bf16(hsvB, b65, acc, 0, 0, 0);
    }
    // D layout (m74/m101): col = lane&31, row = (r&3)+8*(r>>2)+4*(lane>>5)
    #pragma unroll
    for (int r = 0; r < 16; r++) {
      int row = (r & 3) + 8 * (r >> 2) + 4 * kg;
      int oe = (tile << 5) + row;
      if (oe < ecnt) msgbuf[(size_t)oe * WID + col] = f2bf(acc[r]);
    }
  }
}

// ---- node update: 4 thr/node x 8 ch, uint4 msg loads, vector stores --
__global__ void k_update(const unsigned short* __restrict__ msg1,
                         const unsigned short* __restrict__ msg2,
                         const unsigned int* __restrict__ start1, const unsigned int* __restrict__ cnt1,
                         const unsigned int* __restrict__ start2, const unsigned int* __restrict__ cnt2,
                         const float* __restrict__ root1, const float* __restrict__ root2,
                         const float* __restrict__ bias1, const float* __restrict__ bias2,
                         float* __restrict__ h, unsigned short* __restrict__ hbf,
                         int last, const float* __restrict__ fc2w, const float* __restrict__ fc2b,
                         float* __restrict__ out, int n_nodes) {
  __shared__ float rs[WID * WID];
  __shared__ float bs[WID];
  __shared__ float hsh[64][WID + 1];   // +1 pad: nl-varying reads land on distinct banks
  int tid = threadIdx.x;
  for (int i = tid; i < WID * WID; i += 256) rs[i] = root1[i] + root2[i];
  if (tid < WID) bs[tid] = bias1[tid] + bias2[tid];
  int nl = tid >> 2, qc = (tid & 3) << 3;
  int n = blockIdx.x * 64 + nl;
  bool ok = (n < n_nodes);
  if (ok) {
    float4 va = *(const float4*)(h + (size_t)n * WID + qc);
    float4 vb = *(const float4*)(h + (size_t)n * WID + qc + 4);
    hsh[nl][qc+0]=va.x; hsh[nl][qc+1]=va.y; hsh[nl][qc+2]=va.z; hsh[nl][qc+3]=va.w;
    hsh[nl][qc+4]=vb.x; hsh[nl][qc+5]=vb.y; hsh[nl][qc+6]=vb.z; hsh[nl][qc+7]=vb.w;
  }
  __syncthreads();
  if (!ok) return;
  unsigned int b1 = start1[n], c1 = cnt1[n];
  unsigned int b2 = start2[n], c2 = cnt2[n];
  float s1[8] = {0,0,0,0,0,0,0,0}, s2[8] = {0,0,0,0,0,0,0,0};
  for (unsigned int k = 0; k < c1; k++) {
    uint4 mw = *(const uint4*)(msg1 + (size_t)(b1 + k) * WID + qc);
    s1[0] += bf2f((unsigned short)(mw.x & 0xffffu)); s1[1] += bf2f((unsigned short)(mw.x >> 16));
    s1[2] += bf2f((unsigned short)(mw.y & 0xffffu)); s1[3] += bf2f((unsigned short)(mw.y >> 16));
    s1[4] += bf2f((unsigned short)(mw.z & 0xffffu)); s1[5] += bf2f((unsigned short)(mw.z >> 16));
    s1[6] += bf2f((unsigned short)(mw.w & 0xffffu)); s1[7] += bf2f((unsigned short)(mw.w >> 16));
  }
  for (unsigned int k = 0; k < c2; k++) {
    uint4 mw = *(const uint4*)(msg2 + (size_t)(b2 + k) * WID + qc);
    s2[0] += bf2f((unsigned short)(mw.x & 0xffffu)); s2[1] += bf2f((unsigned short)(mw.x >> 16));
    s2[2] += bf2f((unsigned short)(mw.y & 0xffffu)); s2[3] += bf2f((unsigned short)(mw.y >> 16));
    s2[4] += bf2f((unsigned short)(mw.z & 0xffffu)); s2[5] += bf2f((unsigned short)(mw.z >> 16));
    s2[6] += bf2f((unsigned short)(mw.w & 0xffffu)); s2[7] += bf2f((unsigned short)(mw.w >> 16));
  }
  float c1f = (float)(c1 ? c1 : 1u), c2f = (float)(c2 ? c2 : 1u);
  float v[8];
  #pragma unroll
  for (int j = 0; j < 8; j++) v[j] = s1[j] / c1f + s2[j] / c2f + bs[qc + j];
  #pragma unroll
  for (int i = 0; i < WID; i++) {
    float hv = hsh[nl][i];
    #pragma unroll
    for (int j = 0; j < 8; j++) v[j] += hv * rs[i * WID + qc + j];
  }
  #pragma unroll
  for (int j = 0; j < 8; j++) v[j] = fmaxf(v[j], 0.f);
  *(float4*)(h + (size_t)n * WID + qc)     = make_float4(v[0], v[1], v[2], v[3]);
  *(float4*)(h + (size_t)n * WID + qc + 4) = make_float4(v[4], v[5], v[6], v[7]);
  unsigned int pw0 = (unsigned int)f2bf(v[0]) | ((unsigned int)f2bf(v[1]) << 16);
  unsigned int pw1 = (unsigned int)f2bf(v[2]) | ((unsigned int)f2bf(v[3]) << 16);
  unsigned int pw2 = (unsigned int)f2bf(v[4]) | ((unsigned int)f2bf(v[5]) << 16);
  unsigned int pw3 = (unsigned int)f2bf(v[6]) | ((unsigned int)f2bf(v[7]) << 16);
  *(uint4*)(hbf + (size_t)n * WID + qc) = make_uint4(pw0, pw1, pw2, pw3);
  if (last) {
    float pv = 0.f;
    #pragma unroll
    for (int j = 0; j < 8; j++) pv += v[j] * fc2w[qc + j];
    pv += __shfl_xor(pv, 1, 4);
    pv += __shfl_xor(pv, 2, 4);
    if ((tid & 3) == 0) out[n] = pv + fc2b[0];
  }
}

extern "C" void kernel_launch(void* const* d_in, const int* in_sizes, int n_in,
                              void* d_out, int out_size, void* d_ws, size_t ws_size,
                              hipStream_t stream) {
  const float* x    = (const float*)d_in[0];
  const int*   ei   = (const int*)d_in[1];
  const float* ea   = (const float*)d_in[2];
  const int*   eib  = (const int*)d_in[3];
  const float* eab  = (const float*)d_in[4];
  const float* fc1w = (const float*)d_in[5];
  const float* fc1b = (const float*)d_in[6];
  const float* k1w1 = (const float*)d_in[7];
  const float* k1b1 = (const float*)d_in[8];
  const float* k1w2 = (const float*)d_in[9];
  const float* k1b2 = (const float*)d_in[10];
  const float* k1w3 = (const float*)d_in[11];
  const float* k1b3 = (const float*)d_in[12];
  const float* k2w1 = (const float*)d_in[13];
  const float* k2b1 = (const float*)d_in[14];
  const float* k2w2 = (const float*)d_in[15];
  const float* k2b2 = (const float*)d_in[16];
  const float* k2w3 = (const float*)d_in[17];
  const float* k2b3 = (const float*)d_in[18];
  const float* root1 = (const float*)d_in[19];
  const float* bias1 = (const float*)d_in[20];
  const float* root2 = (const float*)d_in[21];
  const float* bias2 = (const float*)d_in[22];
  const float* fc2w = (const float*)d_in[23];
  const float* fc2b = (const float*)d_in[24];
  float* out = (float*)d_out;

  const int n_nodes = in_sizes[0];
  const int E  = in_sizes[1] / 2;
  const int EB = in_sizes[3] / 2;

  char* ws = (char*)d_ws;
  size_t off = 0;
  auto alloc = [&](size_t bytes) -> void* {
    void* p = ws + off;
    off = (off + bytes + 255) & ~(size_t)255;
    return p;
  };
  unsigned short* h3s1 = (unsigned short*)alloc((size_t)E * WID * 2);
  unsigned short* h3s2 = (unsigned short*)alloc((size_t)EB * WID * 2);
  unsigned short* w1b  = (unsigned short*)alloc((size_t)W32_ELEMS * 2);
  unsigned short* w2b  = (unsigned short*)alloc((size_t)W32_ELEMS * 2);
  float* h             = (float*)alloc((size_t)n_nodes * WID * 4);
  unsigned short* hbf  = (unsigned short*)alloc((size_t)n_nodes * WID * 2);
  unsigned short* msg1 = (unsigned short*)alloc((size_t)E * WID * 2);
  unsigned short* msg2 = (unsigned short*)alloc((size_t)EB * WID * 2);
  unsigned int* cnt12  = (unsigned int*)alloc((size_t)2 * n_nodes * 4);  // cnt1||cnt2 contiguous
  unsigned int* cnt1 = cnt12;
  unsigned int* cnt2 = cnt12 + n_nodes;
  unsigned int* start1 = (unsigned int*)alloc((size_t)n_nodes * 4);
  unsigned int* start2 = (unsigned int*)alloc((size_t)n_nodes * 4);
  unsigned int* rank1  = (unsigned int*)alloc((size_t)E * 4);
  unsigned int* rank2  = (unsigned int*)alloc((size_t)EB * 4);
  int* ssrc1 = (int*)alloc((size_t)E * 4);
  int* ssrc2 = (int*)alloc((size_t)EB * 4);
  unsigned int* partials = (unsigned int*)alloc((size_t)1024 * 4);
  (void)ws_size; (void)n_in; (void)out_size;

  const int n2 = 2 * n_nodes;
  const int nb = (n2 + 255) / 256;      // scan blocks (391 for N=50000)
  const int nbC = (E + EB + 255) / 256;
  const int nbH = (n_nodes * WID + 255) / 256;
  const int nbP = (2 * W32_ELEMS + 255) / 256;
  const int nbE = (E + 255) / 256;
  const int nbEB = (EB + 255) / 256;

  // ---- prologue: fused cnt/h0/pack, then scan, then fused edge MLP ----
  hipMemsetAsync(cnt12, 0, (size_t)n2 * 4, stream);
  k_pro<<<nbC + nbH + nbP, 256, 0, stream>>>(ei, E, eib, EB, cnt12, n_nodes, rank1, rank2,
                                             x, fc1w, fc1b, h, hbf,
                                             k1w3, k1b3, w1b, k2w3, k2b3, w2b, nbC, nbH);
  k_scan1<<<nb, 256, 0, stream>>>(cnt12, partials, n2);
  k_scan2<<<1, 1024, 0, stream>>>(partials, nb);
  k_scan3<<<nb, 256, 0, stream>>>(cnt12, partials, start1, start2, n_nodes, E);
  k_emlp2<<<nbE + nbEB, 256, 0, stream>>>(ea, ei, E, rank1, start1, k1w1, k1b1, k1w2, k1b2, h3s1, ssrc1,
                                          eab, eib, EB, rank2, start2, k2w1, k2b1, k2w2, k2b2, h3s2, ssrc2,
                                          nbE);

  const int GRID = 512;
  int B1 = (int)(((long long)GRID * E) / (E + EB));
  if (B1 < 1) B1 = 1;
  if (B1 > GRID - 1) B1 = GRID - 1;

  for (int t = 0; t < DEPTH; t++) {
    k_msg32<<<GRID, 512, 0, stream>>>(hbf, h3s1, ssrc1, E, w1b, msg1,
                                      h3s2, ssrc2, EB, w2b, msg2, B1);
    int last = (t == DEPTH - 1);
    k_update<<<(n_nodes + 63) / 64, 256, 0, stream>>>(msg1, msg2, start1, cnt1, start2, cnt2,
                                                      root1, root2, bias1, bias2, h, hbf,
                                                      last, fc2w, fc2b, out, n_nodes);
  }
}